// Round 1
// baseline (2597.241 us; speedup 1.0000x reference)
//
#include <hip/hip_runtime.h>
#include <math.h>

#define NPIX 262144
#define CDIM 434
#define KCLS 14
#define MPROTO 10
#define KM 140          // KCLS*MPROTO
#define JPAD 144        // padded col count for GEMM
#define CPAD 448        // padded C (28 chunks of 16)
#define INV_EPS 20.0f   // 1/0.05

// ---- workspace float offsets ----
#define OFF_S     0        // [14]
#define OFF_B     16       // [14]
#define OFF_CNT   32       // [140]
#define OFF_C1    172      // [140]
#define OFF_C2    312      // [140]
#define OFF_C3    452      // [140]
#define OFF_ALPHA 592      // [140]
#define OFF_F     736      // [140*434 = 60760]
#define ZERO_N    61496    // zero [0, ZERO_N)
#define OFF_PT    61504    // [448*144 = 64512] protos^T padded
#define OFF_PN    126016   // [140*434] normalized protos
#define OFF_STATS 186784   // [N*4] float4 per row: mu, rstd, linv, 0
#define OFF_BETA  1235360  // [N]
#define OFF_ACCA  1497504  // [N] int
#define OFF_CORR  1759648  // [N] int

__device__ __forceinline__ float wredsum(float v) {
#pragma unroll
  for (int off = 32; off > 0; off >>= 1) v += __shfl_xor(v, off, 64);
  return v;
}

// ---------------- zero small ws region ----------------
__global__ void k_zero(float* ws) {
  int i = blockIdx.x * 256 + threadIdx.x;
  if (i < ZERO_N) ws[i] = 0.f;
}

// ---------------- l2-normalize prototypes; write pn and padded transpose pT ----------------
__global__ void k_protonorm(const float* __restrict__ protos, float* __restrict__ pn,
                            float* __restrict__ pT) {
  int j = blockIdx.x;          // 0..143
  int lane = threadIdx.x;      // 64
  float x[7];
  float ss = 0.f;
#pragma unroll
  for (int i = 0; i < 7; i++) {
    int c = lane + 64 * i;
    float v = (j < KM && c < CDIM) ? protos[(size_t)j * CDIM + c] : 0.f;
    x[i] = v;
    ss += v * v;
  }
  ss = wredsum(ss);
  float rinv = 1.f / fmaxf(sqrtf(ss), 1e-12f);
#pragma unroll
  for (int i = 0; i < 7; i++) {
    int c = lane + 64 * i;   // covers 0..447 exactly
    float v = (j < KM && c < CDIM) ? x[i] * rinv : 0.f;
    if (j < KM && c < CDIM) pn[(size_t)j * CDIM + c] = v;
    pT[(size_t)c * JPAD + j] = v;
  }
}

// ---------------- per-row LN + l2 stats ----------------
__global__ __launch_bounds__(256) void k_rowstats(const float* __restrict__ feat,
                                                  const float* __restrict__ g,
                                                  const float* __restrict__ b,
                                                  float4* __restrict__ stats) {
  int wave = threadIdx.x >> 6, lane = threadIdx.x & 63;
  int n = blockIdx.x * 4 + wave;
  const float* row = feat + (size_t)n * CDIM;
  float x[7];
  float s1 = 0.f;
#pragma unroll
  for (int i = 0; i < 7; i++) {
    int c = lane + 64 * i;
    x[i] = (c < CDIM) ? row[c] : 0.f;
    s1 += x[i];
  }
  s1 = wredsum(s1);
  float mu = s1 / (float)CDIM;
  float s2 = 0.f;
#pragma unroll
  for (int i = 0; i < 7; i++) {
    int c = lane + 64 * i;
    float d = (c < CDIM) ? (x[i] - mu) : 0.f;
    s2 += d * d;
  }
  s2 = wredsum(s2);
  float rstd = rsqrtf(s2 / (float)CDIM + 1e-5f);
  float s3 = 0.f;
#pragma unroll
  for (int i = 0; i < 7; i++) {
    int c = lane + 64 * i;
    if (c < CDIM) {
      float y = (x[i] - mu) * rstd * g[c] + b[c];
      s3 += y * y;
    }
  }
  s3 = wredsum(s3);
  float linv = 1.f / fmaxf(sqrtf(s3), 1e-12f);
  if (lane == 0) stats[n] = make_float4(mu, rstd, linv, 0.f);
}

// ---------------- GEMM: logits[n][j] = _c[n] . pnorm[j], j<140 ----------------
// 128 rows/block, 144 padded cols, 256 threads, 8x9 register tile
__global__ __launch_bounds__(256) void k_gemm(const float* __restrict__ feat,
                                              const float4* __restrict__ stats,
                                              const float* __restrict__ g,
                                              const float* __restrict__ b,
                                              const float* __restrict__ pT,
                                              float* __restrict__ logits) {
  __shared__ __align__(16) float As[128 * 20];
  __shared__ __align__(16) float Bs[JPAD * 20];
  int tid = threadIdx.x;
  int tx = tid & 15, ty = tid >> 4;
  int n0 = blockIdx.x * 128;
  float acc[8][9];
#pragma unroll
  for (int i = 0; i < 8; i++)
#pragma unroll
    for (int s = 0; s < 9; s++) acc[i][s] = 0.f;

  for (int c0 = 0; c0 < CPAD; c0 += 16) {
    // stage A (apply LN+l2 on the fly): 128x16
#pragma unroll
    for (int it = 0; it < 8; it++) {
      int idx = tid + 256 * it;
      int c = idx & 15, r = idx >> 4;
      int cg = c0 + c;
      float v = 0.f;
      if (cg < CDIM) {
        float xx = feat[(size_t)(n0 + r) * CDIM + cg];
        float4 st = stats[n0 + r];
        v = ((xx - st.x) * st.y * g[cg] + b[cg]) * st.z;
      }
      As[r * 20 + c] = v;
    }
    // stage B: 144x16 from padded transpose
#pragma unroll
    for (int it = 0; it < 9; it++) {
      int idx = tid + 256 * it;
      int c = idx / JPAD;
      int jj = idx - c * JPAD;
      Bs[jj * 20 + c] = pT[(size_t)(c0 + c) * JPAD + jj];
    }
    __syncthreads();
#pragma unroll
    for (int c = 0; c < 16; c += 4) {
      float4 av[8], bv[9];
#pragma unroll
      for (int i = 0; i < 8; i++) av[i] = *(const float4*)&As[(ty + 16 * i) * 20 + c];
#pragma unroll
      for (int s = 0; s < 9; s++) bv[s] = *(const float4*)&Bs[(tx + 16 * s) * 20 + c];
#pragma unroll
      for (int i = 0; i < 8; i++)
#pragma unroll
        for (int s = 0; s < 9; s++) {
          acc[i][s] += av[i].x * bv[s].x + av[i].y * bv[s].y +
                       av[i].z * bv[s].z + av[i].w * bv[s].w;
        }
    }
    __syncthreads();
  }
#pragma unroll
  for (int i = 0; i < 8; i++) {
    int n = n0 + ty + 16 * i;
#pragma unroll
    for (int s = 0; s < 9; s++) {
      int j = tx + 16 * s;
      if (j < KM) logits[(size_t)n * KM + j] = acc[i][s];
    }
  }
}

// ---------------- out_seg = LN_K(max_m logits), pred, correct ----------------
__global__ __launch_bounds__(256) void k_seg(const float* __restrict__ logits,
                                             const float* __restrict__ mg,
                                             const float* __restrict__ mb,
                                             const int* __restrict__ gt,
                                             float* __restrict__ out_seg,
                                             int* __restrict__ correct) {
  __shared__ float buf[4][KM];
  int wave = threadIdx.x >> 6, lane = threadIdx.x & 63;
  int n = blockIdx.x * 4 + wave;
  const float* row = logits + (size_t)n * KM;
  for (int j = lane; j < KM; j += 64) buf[wave][j] = row[j];
  __syncthreads();
  bool act = lane < KCLS;
  float v = -1e30f;
  if (act) {
    v = buf[wave][lane * MPROTO];
#pragma unroll
    for (int m = 1; m < MPROTO; m++) v = fmaxf(v, buf[wave][lane * MPROTO + m]);
  }
  float s = act ? v : 0.f;
#pragma unroll
  for (int off = 1; off < 16; off <<= 1) s += __shfl_xor(s, off, 16);
  float mu = s / (float)KCLS;
  float d = act ? (v - mu) : 0.f;
  float s2 = d * d;
#pragma unroll
  for (int off = 1; off < 16; off <<= 1) s2 += __shfl_xor(s2, off, 16);
  float rstd = rsqrtf(s2 / (float)KCLS + 1e-5f);
  float gk = act ? mg[lane] : 0.f;
  float bk = act ? mb[lane] : 0.f;
  float o = (v - mu) * rstd * gk + bk;
  if (act) out_seg[(size_t)n * KCLS + lane] = o;
  // argmax with first-index tie-break
  float bo = act ? o : -1e30f;
  int bi = act ? lane : (1 << 30);
#pragma unroll
  for (int off = 1; off < 16; off <<= 1) {
    float oo = __shfl_xor(bo, off, 16);
    int oi = __shfl_xor(bi, off, 16);
    if (oo > bo || (oo == bo && oi < bi)) { bo = oo; bi = oi; }
  }
  if (lane == 0) correct[n] = (bi == gt[n]) ? 1 : 0;
}

// ---------------- sinkhorn pass: per-class S (sum of exp) and B (count) ----------------
__global__ __launch_bounds__(256) void k_sink_sb(const float* __restrict__ logits,
                                                 const int* __restrict__ gt,
                                                 float* __restrict__ Sg,
                                                 float* __restrict__ Bg) {
  __shared__ float sS[KCLS];
  __shared__ float sB[KCLS];
  int tid = threadIdx.x;
  if (tid < KCLS) { sS[tid] = 0.f; sB[tid] = 0.f; }
  __syncthreads();
  int n = blockIdx.x * 256 + tid;
  int k = gt[n];
  const float* sp = logits + (size_t)n * KM + k * MPROTO;
  float e = 0.f;
#pragma unroll
  for (int m = 0; m < MPROTO; m++) e += expf(sp[m] * INV_EPS);
  atomicAdd(&sS[k], e);
  atomicAdd(&sB[k], 1.f);
  __syncthreads();
  if (tid < KCLS) {
    atomicAdd(&Sg[tid], sS[tid]);
    atomicAdd(&Bg[tid], sB[tid]);
  }
}

__global__ void k_alpha_init(const float* __restrict__ Sg, float* __restrict__ alpha) {
  int j = threadIdx.x;
  if (j < KM) alpha[j] = 1.f / fmaxf(Sg[j / MPROTO], 1e-12f);
}

// column sums with beta == 1
__global__ __launch_bounds__(256) void k_col1(const float* __restrict__ logits,
                                              const int* __restrict__ gt,
                                              float* __restrict__ csum) {
  __shared__ float sc[KM];
  int tid = threadIdx.x;
  for (int j = tid; j < KM; j += 256) sc[j] = 0.f;
  __syncthreads();
  int n = blockIdx.x * 256 + tid;
  int k = gt[n];
  const float* sp = logits + (size_t)n * KM + k * MPROTO;
#pragma unroll
  for (int m = 0; m < MPROTO; m++) atomicAdd(&sc[k * MPROTO + m], expf(sp[m] * INV_EPS));
  __syncthreads();
  for (int j = tid; j < KM; j += 256) atomicAdd(&csum[j], sc[j]);
}

__global__ void k_alpha_up(const float* __restrict__ csum, float* __restrict__ alpha) {
  int j = threadIdx.x;
  if (j < KM) {
    float a = alpha[j];
    float c = a * csum[j];
    alpha[j] = a / (fmaxf(c, 1e-12f) * (float)MPROTO);
  }
}

// fused: row normalize (update beta) + accumulate next column sums
__global__ __launch_bounds__(256) void k_rowcol(const float* __restrict__ logits,
                                                const int* __restrict__ gt,
                                                const float* __restrict__ alpha,
                                                const float* __restrict__ Bg,
                                                float* __restrict__ beta,
                                                float* __restrict__ cnext, int first) {
  __shared__ float sc[KM];
  int tid = threadIdx.x;
  for (int j = tid; j < KM; j += 256) sc[j] = 0.f;
  __syncthreads();
  int n = blockIdx.x * 256 + tid;
  int k = gt[n];
  const float* sp = logits + (size_t)n * KM + k * MPROTO;
  const float* al = alpha + k * MPROTO;
  float e[MPROTO];
  float t = 0.f;
#pragma unroll
  for (int m = 0; m < MPROTO; m++) {
    e[m] = expf(sp[m] * INV_EPS);
    t += e[m] * al[m];
  }
  float bprev = first ? 1.f : beta[n];
  float r = bprev * t;
  float Bc = fmaxf(Bg[k], 1.f);
  float bnew = bprev / (fmaxf(r, 1e-12f) * Bc);
  beta[n] = bnew;
#pragma unroll
  for (int m = 0; m < MPROTO; m++) atomicAdd(&sc[k * MPROTO + m], e[m] * bnew);
  __syncthreads();
  for (int j = tid; j < KM; j += 256) atomicAdd(&cnext[j], sc[j]);
}

// final: argmax -> proto_target, assignment for accumulation
__global__ __launch_bounds__(256) void k_assign(const float* __restrict__ logits,
                                                const int* __restrict__ gt,
                                                const float* __restrict__ alpha,
                                                const int* __restrict__ correct,
                                                float* __restrict__ ptarget,
                                                int* __restrict__ acc_a) {
  int n = blockIdx.x * 256 + threadIdx.x;
  int k = gt[n];
  const float* sp = logits + (size_t)n * KM + k * MPROTO;
  const float* al = alpha + k * MPROTO;
  float best = -1.f;
  int bi = 0;
#pragma unroll
  for (int m = 0; m < MPROTO; m++) {
    float L = expf(sp[m] * INV_EPS) * al[m];
    if (L > best) { best = L; bi = m; }
  }
  ptarget[n] = (float)(bi + MPROTO * k);
  acc_a[n] = correct[n] ? (k * MPROTO + bi) : -1;
}

// ---------------- f accumulation: f[j][:] += _c rows of correct assigned pixels ----------------
__global__ __launch_bounds__(256) void k_faccum(const float* __restrict__ feat,
                                                const float4* __restrict__ stats,
                                                const float* __restrict__ g,
                                                const float* __restrict__ b,
                                                const int* __restrict__ acc_a,
                                                float* __restrict__ f,
                                                float* __restrict__ cnt) {
  __shared__ float accf[KM * 33];
  __shared__ int al[256];
  __shared__ float cl[KM];
  int tid = threadIdx.x;
  int tc = tid & 31, tp = tid >> 5;   // 32 channels x 8 pixel-lanes
  int c0 = blockIdx.y * 32;
  int w = min(32, CDIM - c0);
  for (int i = tid; i < KM * 33; i += 256) accf[i] = 0.f;
  if (blockIdx.y == 0)
    for (int i = tid; i < KM; i += 256) cl[i] = 0.f;
  __syncthreads();
  float gg = 0.f, bb = 0.f;
  if (tc < w) { gg = g[c0 + tc]; bb = b[c0 + tc]; }
  int base0 = blockIdx.x * (NPIX / 32);  // 8192 pixels per block
  for (int sup = 0; sup < NPIX / 32; sup += 256) {
    int pbase = base0 + sup;
    al[tid] = acc_a[pbase + tid];
    __syncthreads();
    for (int sub = 0; sub < 256; sub += 8) {
      int a = al[sub + tp];
      if (a >= 0) {
        int p = pbase + sub + tp;
        if (tc < w) {
          float4 st = stats[p];
          float xx = feat[(size_t)p * CDIM + c0 + tc];
          float y = ((xx - st.x) * st.y * gg + bb) * st.z;
          atomicAdd(&accf[a * 33 + tc], y);
        }
        if (blockIdx.y == 0 && tc == 0) atomicAdd(&cl[a], 1.f);
      }
    }
    __syncthreads();
  }
  for (int j = tp; j < KM; j += 8)
    if (tc < w) atomicAdd(&f[(size_t)j * CDIM + c0 + tc], accf[j * 33 + tc]);
  if (blockIdx.y == 0)
    for (int i = tid; i < KM; i += 256) atomicAdd(&cnt[i], cl[i]);
}

// ---------------- momentum update + final l2norm ----------------
__global__ void k_momentum(const float* __restrict__ pn, const float* __restrict__ f,
                           const float* __restrict__ cnt, float* __restrict__ outp) {
  int j = blockIdx.x;   // 0..139
  int lane = threadIdx.x;
  float fv[7];
  float ss = 0.f;
#pragma unroll
  for (int i = 0; i < 7; i++) {
    int c = lane + 64 * i;
    fv[i] = (c < CDIM) ? f[(size_t)j * CDIM + c] : 0.f;
    ss += fv[i] * fv[i];
  }
  ss = wredsum(ss);
  float rinv = 1.f / fmaxf(sqrtf(ss), 1e-12f);
  bool doupd = cnt[j] > 0.f;
  float sel[7];
  float s2 = 0.f;
#pragma unroll
  for (int i = 0; i < 7; i++) {
    int c = lane + 64 * i;
    float pv = (c < CDIM) ? pn[(size_t)j * CDIM + c] : 0.f;
    float u = 0.999f * pv + 0.001f * (fv[i] * rinv);
    sel[i] = doupd ? u : pv;
    s2 += sel[i] * sel[i];
  }
  s2 = wredsum(s2);
  float r2 = 1.f / fmaxf(sqrtf(s2), 1e-12f);
#pragma unroll
  for (int i = 0; i < 7; i++) {
    int c = lane + 64 * i;
    if (c < CDIM) outp[(size_t)j * CDIM + c] = sel[i] * r2;
  }
}

extern "C" void kernel_launch(void* const* d_in, const int* in_sizes, int n_in,
                              void* d_out, int out_size, void* d_ws, size_t ws_size,
                              hipStream_t stream) {
  const float* feat = (const float*)d_in[0];
  const float* protos = (const float*)d_in[1];
  const float* fg = (const float*)d_in[2];
  const float* fb = (const float*)d_in[3];
  const float* mg = (const float*)d_in[4];
  const float* mb = (const float*)d_in[5];
  const int* gt = (const int*)d_in[6];

  float* out = (float*)d_out;
  float* out_seg = out;                              // [N, K]
  float* logits = out + (size_t)NPIX * KCLS;         // [N, KM]
  float* ptarget = logits + (size_t)NPIX * KM;       // [N]
  float* newp = ptarget + NPIX;                      // [KM, C]

  float* ws = (float*)d_ws;
  float* Sg = ws + OFF_S;
  float* Bg = ws + OFF_B;
  float* cnt = ws + OFF_CNT;
  float* c1 = ws + OFF_C1;
  float* c2 = ws + OFF_C2;
  float* c3 = ws + OFF_C3;
  float* alpha = ws + OFF_ALPHA;
  float* fbuf = ws + OFF_F;
  float* pT = ws + OFF_PT;
  float* pn = ws + OFF_PN;
  float4* stats = (float4*)(ws + OFF_STATS);
  float* beta = ws + OFF_BETA;
  int* acc_a = (int*)(ws + OFF_ACCA);
  int* correct = (int*)(ws + OFF_CORR);

  k_zero<<<(ZERO_N + 255) / 256, 256, 0, stream>>>(ws);
  k_protonorm<<<JPAD, 64, 0, stream>>>(protos, pn, pT);
  k_rowstats<<<NPIX / 4, 256, 0, stream>>>(feat, fg, fb, stats);
  k_gemm<<<NPIX / 128, 256, 0, stream>>>(feat, stats, fg, fb, pT, logits);
  k_seg<<<NPIX / 4, 256, 0, stream>>>(logits, mg, mb, gt, out_seg, correct);
  k_sink_sb<<<NPIX / 256, 256, 0, stream>>>(logits, gt, Sg, Bg);
  k_alpha_init<<<1, 256, 0, stream>>>(Sg, alpha);
  k_col1<<<NPIX / 256, 256, 0, stream>>>(logits, gt, c1);
  k_alpha_up<<<1, 256, 0, stream>>>(c1, alpha);
  k_rowcol<<<NPIX / 256, 256, 0, stream>>>(logits, gt, alpha, Bg, beta, c2, 1);
  k_alpha_up<<<1, 256, 0, stream>>>(c2, alpha);
  k_rowcol<<<NPIX / 256, 256, 0, stream>>>(logits, gt, alpha, Bg, beta, c3, 0);
  k_alpha_up<<<1, 256, 0, stream>>>(c3, alpha);
  k_assign<<<NPIX / 256, 256, 0, stream>>>(logits, gt, alpha, correct, ptarget, acc_a);
  k_faccum<<<dim3(32, 14), 256, 0, stream>>>(feat, stats, fg, fb, acc_a, fbuf, cnt);
  k_momentum<<<KM, 64, 0, stream>>>(pn, fbuf, cnt, newp);
}